// Round 6
// baseline (1970.384 us; speedup 1.0000x reference)
//
#include <hip/hip_runtime.h>
#include <hip/hip_bf16.h>
#include <stdint.h>

typedef __attribute__((ext_vector_type(8))) short short8;
typedef __attribute__((ext_vector_type(4))) short short4v;
typedef __attribute__((ext_vector_type(4))) float f32x4;
typedef __hip_bfloat16 bf16;

#define MFMA16(a, b, c) __builtin_amdgcn_mfma_f32_16x16x32_bf16(a, b, c, 0, 0, 0)

__device__ __forceinline__ short f2bs(float v) {
  bf16 b = __float2bfloat16(v);
  return *reinterpret_cast<short*>(&b);
}
__device__ __forceinline__ float b2f(bf16 b) { return __bfloat162float(b); }

__device__ __forceinline__ short8 cvt8(f32x4 a, f32x4 b) {
  short8 v;
  v[0] = f2bs(a[0]); v[1] = f2bs(a[1]); v[2] = f2bs(a[2]); v[3] = f2bs(a[3]);
  v[4] = f2bs(b[0]); v[5] = f2bs(b[1]); v[6] = f2bs(b[2]); v[7] = f2bs(b[3]);
  return v;
}

// async global->LDS, 16B/lane; LDS dest = wave-uniform base + lane*16.
__device__ __forceinline__ void gl_lds16(const void* g, void* l) {
  __builtin_amdgcn_global_load_lds(
      (const __attribute__((address_space(1))) unsigned int*)g,
      (__attribute__((address_space(3))) unsigned int*)l, 16, 0, 0);
}

// ---------------------------------------------------------------------------
// conv_w: f32 weights -> linear bf16 blobs; biases -> bf16; rpe pre-gathered
// [8 heads][49 q (pad ignored)][64 k-cols (>=49 zero)].
// ---------------------------------------------------------------------------
__global__ __launch_bounds__(256) void k_conv_w3(
    const float* __restrict__ wqkv, const float* __restrict__ bqkv,
    const float* __restrict__ wo,   const float* __restrict__ bo,
    const float* __restrict__ rpe,  const int* __restrict__ relidx,
    bf16* __restrict__ wqkvb, bf16* __restrict__ bqkvb,
    bf16* __restrict__ wob,   bf16* __restrict__ bob,
    bf16* __restrict__ rpew)
{
  int b = blockIdx.x, t = threadIdx.x;
  if (b < 384) {
    long i = (long)b * 2048 + t * 8;
    f32x4 a = *(const f32x4*)(wqkv + i), c = *(const f32x4*)(wqkv + i + 4);
    *reinterpret_cast<short8*>(wqkvb + i) = cvt8(a, c);
  } else if (b < 512) {
    long i = (long)(b - 384) * 2048 + t * 8;
    f32x4 a = *(const f32x4*)(wo + i), c = *(const f32x4*)(wo + i + 4);
    *reinterpret_cast<short8*>(wob + i) = cvt8(a, c);
  } else if (b == 512) {
    for (int j = t; j < 1536; j += 256) bqkvb[j] = __float2bfloat16(bqkv[j]);
    for (int j = t; j < 512;  j += 256) bob[j]  = __float2bfloat16(bo[j]);
  } else {
    int h = b - 513;
    for (int e = t; e < 3136; e += 256) {
      int q = e >> 6, c = e & 63;
      float v = (c < 49) ? rpe[(long)relidx[q * 49 + c] * 8 + h] : 0.f;
      rpew[h * 3136 + e] = __float2bfloat16(v);
    }
  }
}

// ---------------------------------------------------------------------------
// k_fused2: one block per window (512 thr = 8 waves, wave = head).
// QKV GEMM (x f32 read direct, K-sliced dbuf staging) + attention, all fused.
// LDS: sx 2x8KB + 8 wave-private 16KB slabs = 144 KB -> 1 block/CU.
// Output: attnb swizzled rows [2592*64][1024B].
// ---------------------------------------------------------------------------
__global__ __launch_bounds__(512) void k_fused2(
    const float* __restrict__ x,      // [8*15876, 512] f32
    const bf16* __restrict__ wqkvb,   // [1536][512] linear
    const bf16* __restrict__ bqkvb,   // [1536]
    const bf16* __restrict__ rpew,    // [8][49][64]
    char* __restrict__ attnb)         // [165888][1024B] swizzled
{
  __shared__ __align__(16) char sx[2][8192];      // 64 tok x 64 k bf16, swizzled
  __shared__ __align__(16) char slab[8][16384];   // per-wave q/k (later v/p)

  const int tid = threadIdx.x, lane = tid & 63, w = tid >> 6;
  const int r16 = lane & 15, hi = lane >> 4;
  const int wi = blockIdx.x, h = w;

  // staging coords (fixed per thread)
  const int srow = tid >> 3;        // 0..63
  const int c8   = tid & 7;         // 8 f32 per thread
  const int bb = wi / 324, qr = wi - bb * 324, qi = qr / 18, qj = qr - qi * 18;
  const int rowBase = bb * 15876 + qi * 882 + qj * 7;
  const bool valid = srow < 49;
  const float* xrow = x + (size_t)(rowBase + (srow / 7) * 126 + srow % 7) * 512;
  const uint32_t sxoff = (uint32_t)srow * 128 + (uint32_t)((c8 * 16) ^ ((srow & 7) << 4));
  const uint32_t rx = (uint32_t)((r16 & 7) << 4);  // frag-read XOR

  const f32x4 fz = {0.f, 0.f, 0.f, 0.f};

  // ---- stage slice 0 ----
  {
    f32x4 a = fz, b = fz;
    if (valid) { a = *(const f32x4*)(xrow + c8 * 8); b = *(const f32x4*)(xrow + c8 * 8 + 4); }
    *reinterpret_cast<short8*>(sx[0] + sxoff) = cvt8(a, b);
  }
  __syncthreads();

  // ---- QKV GEMM: acc[t][m][n], 768 MFMA/wave over 8 K-slices ----
  f32x4 acc[3][4][4];
  #pragma unroll
  for (int t = 0; t < 3; ++t)
    #pragma unroll
    for (int m = 0; m < 4; ++m)
      #pragma unroll
      for (int n = 0; n < 4; ++n) acc[t][m][n] = fz;

  for (int k0 = 0; k0 < 8; ++k0) {
    f32x4 pa = fz, pb = fz;
    if (k0 < 7 && valid) {          // prefetch next slice (hidden under MFMA)
      pa = *(const f32x4*)(xrow + (k0 + 1) * 64 + c8 * 8);
      pb = *(const f32x4*)(xrow + (k0 + 1) * 64 + c8 * 8 + 4);
    }
    const char* sxc = sx[k0 & 1];
    #pragma unroll
    for (int ks = 0; ks < 2; ++ks) {
      const uint32_t cb = (uint32_t)((ks * 4 + hi) * 16);
      short8 af[4];
      #pragma unroll
      for (int m = 0; m < 4; ++m)
        af[m] = *(const short8*)(sxc + (m * 16 + r16) * 128 + (cb ^ rx));
      #pragma unroll
      for (int t = 0; t < 3; ++t)
        #pragma unroll
        for (int n = 0; n < 4; ++n) {
          short8 bf_ = *(const short8*)(
              wqkvb + (size_t)(t * 512 + h * 64 + n * 16 + r16) * 512 +
              k0 * 64 + ks * 32 + hi * 8);
          #pragma unroll
          for (int m = 0; m < 4; ++m)
            acc[t][m][n] = MFMA16(af[m], bf_, acc[t][m][n]);
        }
    }
    if (k0 < 7)
      *reinterpret_cast<short8*>(sx[(k0 + 1) & 1] + sxoff) = cvt8(pa, pb);
    __syncthreads();
  }

  // ---- wave-private epilogue + attention (no barriers) ----
  char* qs  = slab[w];
  char* ksl = slab[w] + 8192;

  // q,k -> slabs [tok][d] swizzled
  #pragma unroll
  for (int n = 0; n < 4; ++n) {
    int col = n * 16 + r16;
    float bqv = b2f(bqkvb[h * 64 + col]);
    float bkv = b2f(bqkvb[512 + h * 64 + col]);
    #pragma unroll
    for (int m = 0; m < 4; ++m)
      #pragma unroll
      for (int r = 0; r < 4; ++r) {
        int row = m * 16 + hi * 4 + r;
        uint32_t off = (uint32_t)row * 128 + (uint32_t)((2 * col) ^ ((row & 7) << 4));
        *(bf16*)(qs + off)  = __float2bfloat16((acc[0][m][n][r] + bqv) * 0.125f);
        *(bf16*)(ksl + off) = __float2bfloat16(acc[1][m][n][r] + bkv);
      }
  }

  // S = q k^T (wave owns full 64x64)
  f32x4 s[4][4];
  #pragma unroll
  for (int m = 0; m < 4; ++m)
    #pragma unroll
    for (int n = 0; n < 4; ++n) s[m][n] = fz;
  #pragma unroll
  for (int ks = 0; ks < 2; ++ks) {
    const uint32_t cb = (uint32_t)((ks * 4 + hi) * 16);
    short8 qa[4], kb[4];
    #pragma unroll
    for (int m = 0; m < 4; ++m)
      qa[m] = *(const short8*)(qs + (m * 16 + r16) * 128 + (cb ^ rx));
    #pragma unroll
    for (int n = 0; n < 4; ++n)
      kb[n] = *(const short8*)(ksl + (n * 16 + r16) * 128 + (cb ^ rx));
    #pragma unroll
    for (int m = 0; m < 4; ++m)
      #pragma unroll
      for (int n = 0; n < 4; ++n)
        s[m][n] = MFMA16(qa[m], kb[n], s[m][n]);
  }

  // +RPE, mask cols>=49, softmax (16 rows/lane; cols in 4 regs x 16 lanes)
  #pragma unroll
  for (int m = 0; m < 4; ++m)
    #pragma unroll
    for (int rr = 0; rr < 4; ++rr) {
      int qrow = m * 16 + hi * 4 + rr;
      int qc = qrow < 49 ? qrow : 48;
      float vv[4];
      float mx = -1e30f;
      #pragma unroll
      for (int n = 0; n < 4; ++n) {
        int col = n * 16 + r16;
        float sv = s[m][n][rr] + b2f(rpew[h * 3136 + qc * 64 + col]);
        if (col >= 49) sv = -1e30f;
        vv[n] = sv;
        mx = fmaxf(mx, sv);
      }
      mx = fmaxf(mx, __shfl_xor(mx, 1));
      mx = fmaxf(mx, __shfl_xor(mx, 2));
      mx = fmaxf(mx, __shfl_xor(mx, 4));
      mx = fmaxf(mx, __shfl_xor(mx, 8));
      float su = 0.f;
      #pragma unroll
      for (int n = 0; n < 4; ++n) {
        float e = __expf(vv[n] - mx);
        vv[n] = e;
        su += e;
      }
      su += __shfl_xor(su, 1);
      su += __shfl_xor(su, 2);
      su += __shfl_xor(su, 4);
      su += __shfl_xor(su, 8);
      float inv = 1.f / su;
      #pragma unroll
      for (int n = 0; n < 4; ++n) s[m][n][rr] = vv[n] * inv;
    }

  // v -> vs [d][tok] (overwrites q slab): C-layout packs 4 toks -> b64 writes
  char* vs = qs;
  #pragma unroll
  for (int n = 0; n < 4; ++n) {
    int d = n * 16 + r16;
    float bvv = b2f(bqkvb[1024 + h * 64 + d]);
    #pragma unroll
    for (int m = 0; m < 4; ++m) {
      int tok0 = m * 16 + hi * 4;
      short4v pk;
      #pragma unroll
      for (int r = 0; r < 4; ++r) pk[r] = f2bs(acc[2][m][n][r] + bvv);
      *(short4v*)(vs + d * 128 + (uint32_t)((2 * tok0) ^ ((d & 7) << 4))) = pk;
    }
  }

  // P -> ps [q-tok][k-tok] (overwrites k slab)
  char* ps = ksl;
  #pragma unroll
  for (int m = 0; m < 4; ++m)
    #pragma unroll
    for (int n = 0; n < 4; ++n)
      #pragma unroll
      for (int rr = 0; rr < 4; ++rr) {
        int row = m * 16 + hi * 4 + rr, col = n * 16 + r16;
        *(bf16*)(ps + row * 128 + (uint32_t)((2 * col) ^ ((row & 7) << 4))) =
            __float2bfloat16(s[m][n][rr]);
      }

  // O = P @ V
  f32x4 o[4][4];
  #pragma unroll
  for (int m = 0; m < 4; ++m)
    #pragma unroll
    for (int n = 0; n < 4; ++n) o[m][n] = fz;
  #pragma unroll
  for (int ks = 0; ks < 2; ++ks) {
    const uint32_t cb = (uint32_t)((ks * 4 + hi) * 16);
    short8 pf[4], vf[4];
    #pragma unroll
    for (int m = 0; m < 4; ++m)
      pf[m] = *(const short8*)(ps + (m * 16 + r16) * 128 + (cb ^ rx));
    #pragma unroll
    for (int n = 0; n < 4; ++n)
      vf[n] = *(const short8*)(vs + (n * 16 + r16) * 128 + (cb ^ rx));
    #pragma unroll
    for (int m = 0; m < 4; ++m)
      #pragma unroll
      for (int n = 0; n < 4; ++n)
        o[m][n] = MFMA16(pf[m], vf[n], o[m][n]);
  }

  // O -> attnb (swizzled rows; pad rows written with finite garbage, discarded)
  const size_t obase = (size_t)wi * 65536;
  #pragma unroll
  for (int m = 0; m < 4; ++m)
    #pragma unroll
    for (int n = 0; n < 4; ++n) {
      int col = h * 64 + n * 16 + r16;
      #pragma unroll
      for (int r = 0; r < 4; ++r) {
        int row = m * 16 + hi * 4 + r;
        *(bf16*)(attnb + obase + (size_t)row * 1024 +
                 (uint32_t)((2 * col) ^ ((row & 7) << 4))) =
            __float2bfloat16(o[m][n][r]);
      }
    }
}

// ---------------------------------------------------------------------------
// k_out_gemm2: out = attn @ wo^T + bo (f32 un-permute scatter).
// grid 1296 (128 rows each), block 512 = 8 waves (2 row x 4 col tiles);
// A gl_lds double-buffered (fetched ONCE), B streamed from L2.
// ---------------------------------------------------------------------------
__global__ __launch_bounds__(512) void k_out_gemm2(
    const char* __restrict__ attnb,   // [165888][1024B] swizzled
    const bf16* __restrict__ wob,     // [512][512] linear
    const bf16* __restrict__ bob,     // [512]
    float* __restrict__ out)          // [8*15876][512] f32
{
  __shared__ __align__(16) char sA[2][16384];   // 128 rows x 128B slice

  const int tid = threadIdx.x, lane = tid & 63, w = tid >> 6;
  const int r16 = lane & 15, hi = lane >> 4;
  const int mb = blockIdx.x;
  const int mr = w & 1, nc = w >> 1;
  const char* Abase = attnb + (size_t)mb * 131072;
  const uint32_t rx = (uint32_t)((r16 & 7) << 4);
  const f32x4 fz = {0.f, 0.f, 0.f, 0.f};

  // stage slice 0
  #pragma unroll
  for (int j = 0; j < 2; ++j) {
    int ch = w * 2 + j;
    gl_lds16(Abase + (size_t)(ch * 8 + (lane >> 3)) * 1024 + (lane & 7) * 16,
             sA[0] + ch * 1024);
  }
  __syncthreads();

  f32x4 acc[4][8];
  #pragma unroll
  for (int m = 0; m < 4; ++m)
    #pragma unroll
    for (int n = 0; n < 8; ++n) acc[m][n] = fz;

  for (int k0 = 0; k0 < 8; ++k0) {
    if (k0 < 7) {
      #pragma unroll
      for (int j = 0; j < 2; ++j) {
        int ch = w * 2 + j;
        gl_lds16(Abase + (size_t)(ch * 8 + (lane >> 3)) * 1024 + (k0 + 1) * 128 + (lane & 7) * 16,
                 sA[(k0 + 1) & 1] + ch * 1024);
      }
    }
    const char* sa = sA[k0 & 1];
    #pragma unroll
    for (int ks = 0; ks < 2; ++ks) {
      const uint32_t cb = (uint32_t)((ks * 4 + hi) * 16);
      short8 af[4];
      #pragma unroll
      for (int m = 0; m < 4; ++m)
        af[m] = *(const short8*)(sa + (mr * 64 + m * 16 + r16) * 128 + (cb ^ rx));
      #pragma unroll
      for (int n = 0; n < 8; ++n) {
        short8 bf_ = *(const short8*)(
            wob + (size_t)(nc * 128 + n * 16 + r16) * 512 + k0 * 64 + ks * 32 + hi * 8);
        #pragma unroll
        for (int m = 0; m < 4; ++m)
          acc[m][n] = MFMA16(af[m], bf_, acc[m][n]);
      }
    }
    __syncthreads();  // drains gl_lds queue; next buffer ready
  }

  // epilogue: bias + f32 un-permute scatter
  const int wi = mb * 2 + mr;
  const int bb = wi / 324, qr = wi - bb * 324, qi = qr / 18, qj = qr - qi * 18;
  const int rowBase = bb * 15876 + qi * 882 + qj * 7;

  #pragma unroll
  for (int n = 0; n < 8; ++n) {
    int col = nc * 128 + n * 16 + r16;
    float bias = b2f(bob[col]);
    #pragma unroll
    for (int m = 0; m < 4; ++m)
      #pragma unroll
      for (int r = 0; r < 4; ++r) {
        int trow = m * 16 + hi * 4 + r;
        if (trow < 49)
          out[(size_t)(rowBase + (trow / 7) * 126 + trow % 7) * 512 + col] =
              acc[m][n][r] + bias;
      }
  }
}

extern "C" void kernel_launch(void* const* d_in, const int* in_sizes, int n_in,
                              void* d_out, int out_size, void* d_ws, size_t ws_size,
                              hipStream_t stream) {
  const float* x      = (const float*)d_in[0];
  const float* wqkv   = (const float*)d_in[1];
  const float* bqkv   = (const float*)d_in[2];
  const float* wo     = (const float*)d_in[3];
  const float* bo     = (const float*)d_in[4];
  const float* rpe    = (const float*)d_in[5];
  const int*   relidx = (const int*)d_in[6];

  char* ws = (char*)d_ws;
  const size_t OFF_ATTN = 256;
  const size_t SZ_ATTN  = 2592ull * 64 * 1024;        // 169,869,312
  const size_t OFF_WQKV = OFF_ATTN + SZ_ATTN;
  const size_t OFF_WO   = OFF_WQKV + 1536ull * 512 * 2;
  const size_t OFF_BQKV = OFF_WO + 512ull * 512 * 2;
  const size_t OFF_BO   = OFF_BQKV + 3072;
  const size_t OFF_RPEW = OFF_BO + 1024;               // total ~172.4 MB

  char* attnb = ws + OFF_ATTN;
  bf16* wqkvb = (bf16*)(ws + OFF_WQKV);
  bf16* wob   = (bf16*)(ws + OFF_WO);
  bf16* bqkvb = (bf16*)(ws + OFF_BQKV);
  bf16* bob   = (bf16*)(ws + OFF_BO);
  bf16* rpew  = (bf16*)(ws + OFF_RPEW);

  k_conv_w3<<<dim3(521), dim3(256), 0, stream>>>(wqkv, bqkv, wo, bo, rpe, relidx,
                                                 wqkvb, bqkvb, wob, bob, rpew);
  k_fused2<<<dim3(2592), dim3(512), 0, stream>>>(x, wqkvb, bqkvb, rpew, attnb);
  k_out_gemm2<<<dim3(1296), dim3(512), 0, stream>>>(attnb, wob, bob, (float*)d_out);
}

// Round 7
// 1874.830 us; speedup vs baseline: 1.0510x; 1.0510x over previous
//
#include <hip/hip_runtime.h>
#include <hip/hip_bf16.h>
#include <stdint.h>

typedef __attribute__((ext_vector_type(8))) short short8;
typedef __attribute__((ext_vector_type(4))) short short4v;
typedef __attribute__((ext_vector_type(4))) float f32x4;
typedef __hip_bfloat16 bf16;

#define MFMA16(a, b, c) __builtin_amdgcn_mfma_f32_16x16x32_bf16(a, b, c, 0, 0, 0)

__device__ __forceinline__ short f2bs(float v) {
  bf16 b = __float2bfloat16(v);
  return *reinterpret_cast<short*>(&b);
}
__device__ __forceinline__ float b2f(bf16 b) { return __bfloat162float(b); }

__device__ __forceinline__ short8 cvt8(f32x4 a, f32x4 b) {
  short8 v;
  v[0] = f2bs(a[0]); v[1] = f2bs(a[1]); v[2] = f2bs(a[2]); v[3] = f2bs(a[3]);
  v[4] = f2bs(b[0]); v[5] = f2bs(b[1]); v[6] = f2bs(b[2]); v[7] = f2bs(b[3]);
  return v;
}

// async global->LDS, 16B/lane; LDS dest = wave-uniform base + lane*16.
__device__ __forceinline__ void gl_lds16(const void* g, void* l) {
  __builtin_amdgcn_global_load_lds(
      (const __attribute__((address_space(1))) unsigned int*)g,
      (__attribute__((address_space(3))) unsigned int*)l, 16, 0, 0);
}

// ---------------------------------------------------------------------------
// conv_w: f32 weights -> bf16 blobs (wqkv linear; wo SWIZZLED for gl_lds
// staging in out_gemm); biases -> bf16; rpe pre-gathered [8][49pad][64].
// ---------------------------------------------------------------------------
__global__ __launch_bounds__(256) void k_conv_w3(
    const float* __restrict__ wqkv, const float* __restrict__ bqkv,
    const float* __restrict__ wo,   const float* __restrict__ bo,
    const float* __restrict__ rpe,  const int* __restrict__ relidx,
    bf16* __restrict__ wqkvb, bf16* __restrict__ bqkvb,
    char* __restrict__ wob,   bf16* __restrict__ bob,
    bf16* __restrict__ rpew)
{
  int b = blockIdx.x, t = threadIdx.x;
  if (b < 384) {                       // wqkv linear
    long i = (long)b * 2048 + t * 8;
    f32x4 a = *(const f32x4*)(wqkv + i), c = *(const f32x4*)(wqkv + i + 4);
    *reinterpret_cast<short8*>(wqkvb + i) = cvt8(a, c);
  } else if (b < 512) {                // wo swizzled rows [512][1024B]
    long i = (long)(b - 384) * 2048 + t * 8;
    int row = (int)(i >> 9);
    uint32_t g = ((uint32_t)i & 511u) >> 3;
    f32x4 a = *(const f32x4*)(wo + i), c = *(const f32x4*)(wo + i + 4);
    *reinterpret_cast<short8*>(wob + (size_t)row * 1024 + ((g * 16) ^ ((row & 7u) << 4))) = cvt8(a, c);
  } else if (b == 512) {
    for (int j = t; j < 1536; j += 256) bqkvb[j] = __float2bfloat16(bqkv[j]);
    for (int j = t; j < 512;  j += 256) bob[j]  = __float2bfloat16(bo[j]);
  } else {
    int h = b - 513;
    for (int e = t; e < 3136; e += 256) {
      int q = e >> 6, c = e & 63;
      float v = (c < 49) ? rpe[(long)relidx[q * 49 + c] * 8 + h] : 0.f;
      rpew[h * 3136 + e] = __float2bfloat16(v);
    }
  }
}

// ---------------------------------------------------------------------------
// k_fused2: one block per window (512 thr = 8 waves, wave = head).
// QKV GEMM (x f32 read direct, K-sliced dbuf staging) + attention, all fused.
// LDS 144 KB -> 1 block/CU -> 2 waves/SIMD; launch_bounds(512,2) => 256 VGPR
// budget (round-6 lesson: default cap of 128 spilled 5 GB of scratch).
// ---------------------------------------------------------------------------
__global__ __launch_bounds__(512, 2) void k_fused2(
    const float* __restrict__ x,      // [8*15876, 512] f32
    const bf16* __restrict__ wqkvb,   // [1536][512] linear
    const bf16* __restrict__ bqkvb,   // [1536]
    const bf16* __restrict__ rpew,    // [8][49][64]
    char* __restrict__ attnb)         // [165888][1024B] swizzled
{
  __shared__ __align__(16) char sx[2][8192];      // 64 tok x 64 k bf16, swizzled
  __shared__ __align__(16) char slab[8][16384];   // per-wave q/k (later v/p)

  const int tid = threadIdx.x, lane = tid & 63, w = tid >> 6;
  const int r16 = lane & 15, hi = lane >> 4;
  const int wi = blockIdx.x, h = w;

  const int srow = tid >> 3;        // 0..63
  const int c8   = tid & 7;         // 8 f32 per thread
  const int bb = wi / 324, qr = wi - bb * 324, qi = qr / 18, qj = qr - qi * 18;
  const int rowBase = bb * 15876 + qi * 882 + qj * 7;
  const bool valid = srow < 49;
  const float* xrow = x + (size_t)(rowBase + (srow / 7) * 126 + srow % 7) * 512;
  const uint32_t sxoff = (uint32_t)srow * 128 + (uint32_t)((c8 * 16) ^ ((srow & 7) << 4));
  const uint32_t rx = (uint32_t)((r16 & 7) << 4);  // frag-read XOR

  const f32x4 fz = {0.f, 0.f, 0.f, 0.f};

  // ---- stage slice 0 ----
  {
    f32x4 a = fz, b = fz;
    if (valid) { a = *(const f32x4*)(xrow + c8 * 8); b = *(const f32x4*)(xrow + c8 * 8 + 4); }
    *reinterpret_cast<short8*>(sx[0] + sxoff) = cvt8(a, b);
  }
  __syncthreads();

  // ---- QKV GEMM: acc[t][m][n], 768 MFMA/wave over 8 K-slices ----
  f32x4 acc[3][4][4];
  #pragma unroll
  for (int t = 0; t < 3; ++t)
    #pragma unroll
    for (int m = 0; m < 4; ++m)
      #pragma unroll
      for (int n = 0; n < 4; ++n) acc[t][m][n] = fz;

  for (int k0 = 0; k0 < 8; ++k0) {
    f32x4 pa = fz, pb = fz;
    if (k0 < 7 && valid) {          // prefetch next slice (hidden under MFMA)
      pa = *(const f32x4*)(xrow + (k0 + 1) * 64 + c8 * 8);
      pb = *(const f32x4*)(xrow + (k0 + 1) * 64 + c8 * 8 + 4);
    }
    const char* sxc = sx[k0 & 1];
    #pragma unroll
    for (int ks = 0; ks < 2; ++ks) {
      const uint32_t cb = (uint32_t)((ks * 4 + hi) * 16);
      short8 af[4];
      #pragma unroll
      for (int m = 0; m < 4; ++m)
        af[m] = *(const short8*)(sxc + (m * 16 + r16) * 128 + (cb ^ rx));
      #pragma unroll
      for (int t = 0; t < 3; ++t)
        #pragma unroll
        for (int n = 0; n < 4; ++n) {
          short8 bf_ = *(const short8*)(
              wqkvb + (size_t)(t * 512 + h * 64 + n * 16 + r16) * 512 +
              k0 * 64 + ks * 32 + hi * 8);
          #pragma unroll
          for (int m = 0; m < 4; ++m)
            acc[t][m][n] = MFMA16(af[m], bf_, acc[t][m][n]);
        }
    }
    if (k0 < 7)
      *reinterpret_cast<short8*>(sx[(k0 + 1) & 1] + sxoff) = cvt8(pa, pb);
    __syncthreads();
  }

  // ---- wave-private epilogue + attention (no barriers) ----
  char* qs  = slab[w];
  char* ksl = slab[w] + 8192;

  // q,k -> slabs [tok][d] swizzled
  #pragma unroll
  for (int n = 0; n < 4; ++n) {
    int col = n * 16 + r16;
    float bqv = b2f(bqkvb[h * 64 + col]);
    float bkv = b2f(bqkvb[512 + h * 64 + col]);
    #pragma unroll
    for (int m = 0; m < 4; ++m)
      #pragma unroll
      for (int r = 0; r < 4; ++r) {
        int row = m * 16 + hi * 4 + r;
        uint32_t off = (uint32_t)row * 128 + (uint32_t)((2 * col) ^ ((row & 7) << 4));
        *(bf16*)(qs + off)  = __float2bfloat16((acc[0][m][n][r] + bqv) * 0.125f);
        *(bf16*)(ksl + off) = __float2bfloat16(acc[1][m][n][r] + bkv);
      }
  }

  // S = q k^T (wave owns full 64x64)
  f32x4 s[4][4];
  #pragma unroll
  for (int m = 0; m < 4; ++m)
    #pragma unroll
    for (int n = 0; n < 4; ++n) s[m][n] = fz;
  #pragma unroll
  for (int ks = 0; ks < 2; ++ks) {
    const uint32_t cb = (uint32_t)((ks * 4 + hi) * 16);
    short8 qa[4], kb[4];
    #pragma unroll
    for (int m = 0; m < 4; ++m)
      qa[m] = *(const short8*)(qs + (m * 16 + r16) * 128 + (cb ^ rx));
    #pragma unroll
    for (int n = 0; n < 4; ++n)
      kb[n] = *(const short8*)(ksl + (n * 16 + r16) * 128 + (cb ^ rx));
    #pragma unroll
    for (int m = 0; m < 4; ++m)
      #pragma unroll
      for (int n = 0; n < 4; ++n)
        s[m][n] = MFMA16(qa[m], kb[n], s[m][n]);
  }

  // +RPE, mask cols>=49, softmax (rows spread: lane holds 16 rows' 4 col-regs)
  #pragma unroll
  for (int m = 0; m < 4; ++m)
    #pragma unroll
    for (int rr = 0; rr < 4; ++rr) {
      int qrow = m * 16 + hi * 4 + rr;
      int qc = qrow < 49 ? qrow : 48;
      float vv[4];
      float mx = -1e30f;
      #pragma unroll
      for (int n = 0; n < 4; ++n) {
        int col = n * 16 + r16;
        float sv = s[m][n][rr] + b2f(rpew[h * 3136 + qc * 64 + col]);
        if (col >= 49) sv = -1e30f;
        vv[n] = sv;
        mx = fmaxf(mx, sv);
      }
      mx = fmaxf(mx, __shfl_xor(mx, 1));
      mx = fmaxf(mx, __shfl_xor(mx, 2));
      mx = fmaxf(mx, __shfl_xor(mx, 4));
      mx = fmaxf(mx, __shfl_xor(mx, 8));
      float su = 0.f;
      #pragma unroll
      for (int n = 0; n < 4; ++n) {
        float e = __expf(vv[n] - mx);
        vv[n] = e;
        su += e;
      }
      su += __shfl_xor(su, 1);
      su += __shfl_xor(su, 2);
      su += __shfl_xor(su, 4);
      su += __shfl_xor(su, 8);
      float inv = 1.f / su;
      #pragma unroll
      for (int n = 0; n < 4; ++n) s[m][n][rr] = vv[n] * inv;
    }

  // v -> vs [d][tok] (overwrites q slab): C-layout packs 4 toks -> b64 writes
  char* vs = qs;
  #pragma unroll
  for (int n = 0; n < 4; ++n) {
    int d = n * 16 + r16;
    float bvv = b2f(bqkvb[1024 + h * 64 + d]);
    #pragma unroll
    for (int m = 0; m < 4; ++m) {
      int tok0 = m * 16 + hi * 4;
      short4v pk;
      #pragma unroll
      for (int r = 0; r < 4; ++r) pk[r] = f2bs(acc[2][m][n][r] + bvv);
      *(short4v*)(vs + d * 128 + (uint32_t)((2 * tok0) ^ ((d & 7) << 4))) = pk;
    }
  }

  // P -> ps [q-tok][k-tok] (overwrites k slab)
  char* ps = ksl;
  #pragma unroll
  for (int m = 0; m < 4; ++m)
    #pragma unroll
    for (int n = 0; n < 4; ++n)
      #pragma unroll
      for (int rr = 0; rr < 4; ++rr) {
        int row = m * 16 + hi * 4 + rr, col = n * 16 + r16;
        *(bf16*)(ps + row * 128 + (uint32_t)((2 * col) ^ ((row & 7) << 4))) =
            __float2bfloat16(s[m][n][rr]);
      }

  // O = P @ V
  f32x4 o[4][4];
  #pragma unroll
  for (int m = 0; m < 4; ++m)
    #pragma unroll
    for (int n = 0; n < 4; ++n) o[m][n] = fz;
  #pragma unroll
  for (int ks = 0; ks < 2; ++ks) {
    const uint32_t cb = (uint32_t)((ks * 4 + hi) * 16);
    short8 pf[4], vf[4];
    #pragma unroll
    for (int m = 0; m < 4; ++m)
      pf[m] = *(const short8*)(ps + (m * 16 + r16) * 128 + (cb ^ rx));
    #pragma unroll
    for (int n = 0; n < 4; ++n)
      vf[n] = *(const short8*)(vs + (n * 16 + r16) * 128 + (cb ^ rx));
    #pragma unroll
    for (int m = 0; m < 4; ++m)
      #pragma unroll
      for (int n = 0; n < 4; ++n)
        o[m][n] = MFMA16(pf[m], vf[n], o[m][n]);
  }

  // O -> attnb (swizzled rows; pad rows hold finite garbage, discarded later)
  const size_t obase = (size_t)wi * 65536;
  #pragma unroll
  for (int m = 0; m < 4; ++m)
    #pragma unroll
    for (int n = 0; n < 4; ++n) {
      int col = h * 64 + n * 16 + r16;
      #pragma unroll
      for (int r = 0; r < 4; ++r) {
        int row = m * 16 + hi * 4 + r;
        *(bf16*)(attnb + obase + (size_t)row * 1024 +
                 (uint32_t)((2 * col) ^ ((row & 7) << 4))) =
            __float2bfloat16(o[m][n][r]);
      }
    }
}

// ---------------------------------------------------------------------------
// k_out_gemm (round-5 proven: 170 us, VGPR 80): out = attn @ wo^T + bo,
// f32 un-permute scatter. grid 1296x4; block 256 / 4 waves; LDS 32 KB.
// ---------------------------------------------------------------------------
__global__ __launch_bounds__(256) void k_out_gemm(
    const char* __restrict__ attnb,   // [165888][1024B] swizzled
    const char* __restrict__ wob,     // [512][1024B] swizzled
    const bf16* __restrict__ bob,     // [512]
    float* __restrict__ out)          // [8*15876][512] f32
{
  __shared__ __align__(16) char sA[16384];
  __shared__ __align__(16) char sB[16384];

  const int tid = threadIdx.x, lane = tid & 63, w = tid >> 6;
  const int r16 = lane & 15, hi = lane >> 4;
  const int mb = blockIdx.x % 1296, nb = blockIdx.x / 1296;

  const f32x4 fzero = {0.f, 0.f, 0.f, 0.f};
  f32x4 acc[4][4];
  #pragma unroll
  for (int m = 0; m < 4; ++m)
    #pragma unroll
    for (int n = 0; n < 4; ++n) acc[m][n] = fzero;

  const char* Abase = attnb + (size_t)mb * 131072;
  const char* Bbase = wob + (size_t)nb * 131072;

  for (int k0 = 0; k0 < 8; ++k0) {
    if (k0) __syncthreads();
    #pragma unroll
    for (int j = 0; j < 8; ++j) {
      int ch = w * 8 + j;
      if (ch < 16) {
        gl_lds16(Abase + (size_t)(ch * 8 + (lane >> 3)) * 1024 + k0 * 128 + (lane & 7) * 16,
                 sA + ch * 1024);
      } else {
        int c2 = ch - 16;
        gl_lds16(Bbase + (size_t)(c2 * 8 + (lane >> 3)) * 1024 + k0 * 128 + (lane & 7) * 16,
                 sB + c2 * 1024);
      }
    }
    __syncthreads();

    #pragma unroll
    for (int ks = 0; ks < 2; ++ks) {
      uint32_t cb = (uint32_t)((ks * 4 + hi) * 16) ^ ((r16 & 7u) << 4);
      short8 aF[4], bF[4];
      #pragma unroll
      for (int m = 0; m < 4; ++m)
        aF[m] = *reinterpret_cast<const short8*>(sA + ((w & 1) * 64 + m * 16 + r16) * 128 + cb);
      #pragma unroll
      for (int n = 0; n < 4; ++n)
        bF[n] = *reinterpret_cast<const short8*>(sB + ((w >> 1) * 64 + n * 16 + r16) * 128 + cb);
      #pragma unroll
      for (int m = 0; m < 4; ++m)
        #pragma unroll
        for (int n = 0; n < 4; ++n)
          acc[m][n] = MFMA16(aF[m], bF[n], acc[m][n]);
    }
  }

  const int wi = mb * 2 + (w & 1);
  const int bb = wi / 324, qr = wi - bb * 324, qi = qr / 18, qj = qr - qi * 18;
  const int rowBase = bb * 15876 + qi * 882 + qj * 7;
  const int colb = nb * 128 + (w >> 1) * 64;

  #pragma unroll
  for (int n = 0; n < 4; ++n) {
    int col = colb + n * 16 + r16;
    float bias = b2f(bob[col]);
    #pragma unroll
    for (int m = 0; m < 4; ++m)
      #pragma unroll
      for (int r = 0; r < 4; ++r) {
        int row = m * 16 + hi * 4 + r;
        if (row < 49)
          out[(size_t)(rowBase + (row / 7) * 126 + row % 7) * 512 + col] =
              acc[m][n][r] + bias;
      }
  }
}

extern "C" void kernel_launch(void* const* d_in, const int* in_sizes, int n_in,
                              void* d_out, int out_size, void* d_ws, size_t ws_size,
                              hipStream_t stream) {
  const float* x      = (const float*)d_in[0];
  const float* wqkv   = (const float*)d_in[1];
  const float* bqkv   = (const float*)d_in[2];
  const float* wo     = (const float*)d_in[3];
  const float* bo     = (const float*)d_in[4];
  const float* rpe    = (const float*)d_in[5];
  const int*   relidx = (const int*)d_in[6];

  char* ws = (char*)d_ws;
  const size_t OFF_ATTN = 256;
  const size_t SZ_ATTN  = 2592ull * 64 * 1024;        // 169,869,312
  const size_t OFF_WQKV = OFF_ATTN + SZ_ATTN;
  const size_t OFF_WO   = OFF_WQKV + 1536ull * 512 * 2;
  const size_t OFF_BQKV = OFF_WO + 512ull * 1024;
  const size_t OFF_BO   = OFF_BQKV + 3072;
  const size_t OFF_RPEW = OFF_BO + 1024;               // total ~172.4 MB

  char* attnb = ws + OFF_ATTN;
  bf16* wqkvb = (bf16*)(ws + OFF_WQKV);
  char* wob   = ws + OFF_WO;
  bf16* bqkvb = (bf16*)(ws + OFF_BQKV);
  bf16* bob   = (bf16*)(ws + OFF_BO);
  bf16* rpew  = (bf16*)(ws + OFF_RPEW);

  k_conv_w3<<<dim3(521), dim3(256), 0, stream>>>(wqkv, bqkv, wo, bo, rpe, relidx,
                                                 wqkvb, bqkvb, wob, bob, rpew);
  k_fused2<<<dim3(2592), dim3(512), 0, stream>>>(x, wqkvb, bqkvb, rpew, attnb);
  k_out_gemm<<<dim3(1296 * 4), dim3(256), 0, stream>>>(attnb, wob, bob, (float*)d_out);
}

// Round 8
// 1269.975 us; speedup vs baseline: 1.5515x; 1.4763x over previous
//
#include <hip/hip_runtime.h>
#include <hip/hip_bf16.h>
#include <stdint.h>

typedef __attribute__((ext_vector_type(8))) short short8;
typedef __attribute__((ext_vector_type(4))) short short4v;
typedef __attribute__((ext_vector_type(4))) float f32x4;
typedef __hip_bfloat16 bf16;

#define MFMA16(a, b, c) __builtin_amdgcn_mfma_f32_16x16x32_bf16(a, b, c, 0, 0, 0)

__device__ __forceinline__ short f2bs(float v) {
  bf16 b = __float2bfloat16(v);
  return *reinterpret_cast<short*>(&b);
}
__device__ __forceinline__ float b2f(bf16 b) { return __bfloat162float(b); }

__device__ __forceinline__ short8 cvt8(f32x4 a, f32x4 b) {
  short8 v;
  v[0] = f2bs(a[0]); v[1] = f2bs(a[1]); v[2] = f2bs(a[2]); v[3] = f2bs(a[3]);
  v[4] = f2bs(b[0]); v[5] = f2bs(b[1]); v[6] = f2bs(b[2]); v[7] = f2bs(b[3]);
  return v;
}

// async global->LDS, 16B/lane; LDS dest = wave-uniform base + lane*16.
__device__ __forceinline__ void gl_lds16(const void* g, void* l) {
  __builtin_amdgcn_global_load_lds(
      (const __attribute__((address_space(1))) unsigned int*)g,
      (__attribute__((address_space(3))) unsigned int*)l, 16, 0, 0);
}

// ---------------------------------------------------------------------------
// conv_w: f32 weights -> bf16 blobs (wqkv linear; wo SWIZZLED for gl_lds
// staging in out_gemm); biases -> bf16; rpe pre-gathered [8][49pad][64].
// ---------------------------------------------------------------------------
__global__ __launch_bounds__(256) void k_conv_w3(
    const float* __restrict__ wqkv, const float* __restrict__ bqkv,
    const float* __restrict__ wo,   const float* __restrict__ bo,
    const float* __restrict__ rpe,  const int* __restrict__ relidx,
    bf16* __restrict__ wqkvb, bf16* __restrict__ bqkvb,
    char* __restrict__ wob,   bf16* __restrict__ bob,
    bf16* __restrict__ rpew)
{
  int b = blockIdx.x, t = threadIdx.x;
  if (b < 384) {                       // wqkv linear
    long i = (long)b * 2048 + t * 8;
    f32x4 a = *(const f32x4*)(wqkv + i), c = *(const f32x4*)(wqkv + i + 4);
    *reinterpret_cast<short8*>(wqkvb + i) = cvt8(a, c);
  } else if (b < 512) {                // wo swizzled rows [512][1024B]
    long i = (long)(b - 384) * 2048 + t * 8;
    int row = (int)(i >> 9);
    uint32_t g = ((uint32_t)i & 511u) >> 3;
    f32x4 a = *(const f32x4*)(wo + i), c = *(const f32x4*)(wo + i + 4);
    *reinterpret_cast<short8*>(wob + (size_t)row * 1024 + ((g * 16) ^ ((row & 7u) << 4))) = cvt8(a, c);
  } else if (b == 512) {
    for (int j = t; j < 1536; j += 256) bqkvb[j] = __float2bfloat16(bqkv[j]);
    for (int j = t; j < 512;  j += 256) bob[j]  = __float2bfloat16(bo[j]);
  } else {
    int h = b - 513;
    for (int e = t; e < 3136; e += 256) {
      int q = e >> 6, c = e & 63;
      float v = (c < 49) ? rpe[(long)relidx[q * 49 + c] * 8 + h] : 0.f;
      rpew[h * 3136 + e] = __float2bfloat16(v);
    }
  }
}

// ---------------------------------------------------------------------------
// k_fused3: QKV GEMM + attention, wave-pair per head.
// Block = 512 thr = 8 waves = 4 heads x 2 token-halves; 2 blocks/window.
// Per-wave acc[3][2][4] = 96 VGPRs -> fits the observed 128-reg cap.
// LDS 80 KB (x dbuf 16K + 4 head slabs x 16K) -> 2 blocks/CU, 4 waves/SIMD.
// XCD mapping: both blocks of a window adjacent on one XCD (x L2 reuse).
// ---------------------------------------------------------------------------
__global__ __launch_bounds__(512) void k_fused3(
    const float* __restrict__ x,      // [8*15876, 512] f32
    const bf16* __restrict__ wqkvb,   // [1536][512] linear
    const bf16* __restrict__ bqkvb,   // [1536]
    const bf16* __restrict__ rpew,    // [8][49pad][64]
    char* __restrict__ attnb)         // [165888][1024B] swizzled
{
  __shared__ __align__(16) char sx[2][8192];      // 64 tok x 64 k bf16, swizzled
  __shared__ __align__(16) char slab[4][16384];   // per local head: q|k -> v|p

  const int tid = threadIdx.x, lane = tid & 63, w = tid >> 6;
  const int r16 = lane & 15, hi = lane >> 4;
  const int hl = w >> 1;            // local head 0..3
  const int half = w & 1;           // token half: rows half*32..half*32+31

  // window / head-group decode (XCD-paired)
  const int raw = blockIdx.x;       // 0..5183
  const int xcd = raw & 7, slot = raw >> 3;
  const int wi = xcd * 324 + (slot >> 1);
  const int hsel = slot & 1;
  const int h = hsel * 4 + hl;      // global head

  // staging coords
  const int srow = tid >> 3;        // 0..63
  const int c8   = tid & 7;         // 8 f32 per thread
  const int bb = wi / 324, qr = wi - bb * 324, qi = qr / 18, qj = qr - qi * 18;
  const int rowBase = bb * 15876 + qi * 882 + qj * 7;
  const bool valid = srow < 49;
  const float* xrow = x + (size_t)(rowBase + (srow / 7) * 126 + srow % 7) * 512;
  const uint32_t sxoff = (uint32_t)srow * 128 + (uint32_t)((c8 * 16) ^ ((srow & 7) << 4));
  const uint32_t rx = (uint32_t)((r16 & 7) << 4);  // frag-read XOR

  const f32x4 fz = {0.f, 0.f, 0.f, 0.f};

  // ---- stage slice 0 ----
  {
    f32x4 a = fz, b = fz;
    if (valid) { a = *(const f32x4*)(xrow + c8 * 8); b = *(const f32x4*)(xrow + c8 * 8 + 4); }
    *reinterpret_cast<short8*>(sx[0] + sxoff) = cvt8(a, b);
  }
  __syncthreads();

  // ---- QKV GEMM: acc[t][mm][n] over 8 K-slices (384 MFMA/wave) ----
  f32x4 acc[3][2][4];
  #pragma unroll
  for (int t = 0; t < 3; ++t)
    #pragma unroll
    for (int mm = 0; mm < 2; ++mm)
      #pragma unroll
      for (int n = 0; n < 4; ++n) acc[t][mm][n] = fz;

  for (int k0 = 0; k0 < 8; ++k0) {
    f32x4 pa = fz, pb = fz;
    if (k0 < 7 && valid) {
      pa = *(const f32x4*)(xrow + (k0 + 1) * 64 + c8 * 8);
      pb = *(const f32x4*)(xrow + (k0 + 1) * 64 + c8 * 8 + 4);
    }
    const char* sxc = sx[k0 & 1];
    #pragma unroll
    for (int ks = 0; ks < 2; ++ks) {
      const uint32_t cb = (uint32_t)((ks * 4 + hi) * 16);
      short8 af[2];
      #pragma unroll
      for (int mm = 0; mm < 2; ++mm)
        af[mm] = *(const short8*)(sxc + (half * 32 + mm * 16 + r16) * 128 + (cb ^ rx));
      #pragma unroll
      for (int t = 0; t < 3; ++t)
        #pragma unroll
        for (int n = 0; n < 4; ++n) {
          short8 bf_ = *(const short8*)(
              wqkvb + (size_t)(t * 512 + h * 64 + n * 16 + r16) * 512 +
              k0 * 64 + ks * 32 + hi * 8);
          #pragma unroll
          for (int mm = 0; mm < 2; ++mm)
            acc[t][mm][n] = MFMA16(af[mm], bf_, acc[t][mm][n]);
        }
    }
    if (k0 < 7)
      *reinterpret_cast<short8*>(sx[(k0 + 1) & 1] + sxoff) = cvt8(pa, pb);
    __syncthreads();
  }

  // ---- q,k -> head slab [tok][d] swizzled (each wave: its token half) ----
  char* qs  = slab[hl];
  char* ksl = slab[hl] + 8192;
  #pragma unroll
  for (int n = 0; n < 4; ++n) {
    int col = n * 16 + r16;
    float bqv = b2f(bqkvb[h * 64 + col]);
    float bkv = b2f(bqkvb[512 + h * 64 + col]);
    #pragma unroll
    for (int mm = 0; mm < 2; ++mm)
      #pragma unroll
      for (int r = 0; r < 4; ++r) {
        int row = half * 32 + mm * 16 + hi * 4 + r;
        uint32_t off = (uint32_t)row * 128 + (uint32_t)((2 * col) ^ ((row & 7) << 4));
        *(bf16*)(qs + off)  = __float2bfloat16((acc[0][mm][n][r] + bqv) * 0.125f);
        *(bf16*)(ksl + off) = __float2bfloat16(acc[1][mm][n][r] + bkv);
      }
  }
  __syncthreads();   // pair exchange: full q,k visible

  // ---- S = q k^T for this wave's 32 q-rows ----
  f32x4 s[2][4];
  #pragma unroll
  for (int mm = 0; mm < 2; ++mm)
    #pragma unroll
    for (int n = 0; n < 4; ++n) s[mm][n] = fz;
  #pragma unroll
  for (int ks = 0; ks < 2; ++ks) {
    const uint32_t cb = (uint32_t)((ks * 4 + hi) * 16);
    short8 qa[2], kb[4];
    #pragma unroll
    for (int mm = 0; mm < 2; ++mm)
      qa[mm] = *(const short8*)(qs + (half * 32 + mm * 16 + r16) * 128 + (cb ^ rx));
    #pragma unroll
    for (int n = 0; n < 4; ++n)
      kb[n] = *(const short8*)(ksl + (n * 16 + r16) * 128 + (cb ^ rx));
    #pragma unroll
    for (int mm = 0; mm < 2; ++mm)
      #pragma unroll
      for (int n = 0; n < 4; ++n)
        s[mm][n] = MFMA16(qa[mm], kb[n], s[mm][n]);
  }

  // ---- +RPE, mask cols>=49, in-register softmax ----
  #pragma unroll
  for (int mm = 0; mm < 2; ++mm)
    #pragma unroll
    for (int rr = 0; rr < 4; ++rr) {
      int qrow = half * 32 + mm * 16 + hi * 4 + rr;
      int qc = qrow < 49 ? qrow : 48;
      float vv[4];
      float mx = -1e30f;
      #pragma unroll
      for (int n = 0; n < 4; ++n) {
        int col = n * 16 + r16;
        float sv = s[mm][n][rr] + b2f(rpew[h * 3136 + qc * 64 + col]);
        if (col >= 49) sv = -1e30f;
        vv[n] = sv;
        mx = fmaxf(mx, sv);
      }
      mx = fmaxf(mx, __shfl_xor(mx, 1));
      mx = fmaxf(mx, __shfl_xor(mx, 2));
      mx = fmaxf(mx, __shfl_xor(mx, 4));
      mx = fmaxf(mx, __shfl_xor(mx, 8));
      float su = 0.f;
      #pragma unroll
      for (int n = 0; n < 4; ++n) {
        float e = __expf(vv[n] - mx);
        vv[n] = e;
        su += e;
      }
      su += __shfl_xor(su, 1);
      su += __shfl_xor(su, 2);
      su += __shfl_xor(su, 4);
      su += __shfl_xor(su, 8);
      float inv = 1.f / su;
      #pragma unroll
      for (int n = 0; n < 4; ++n) s[mm][n][rr] = vv[n] * inv;
    }
  __syncthreads();   // all reads of q,k done; slabs may be overwritten

  // ---- v -> vs(=qs) [d][tok]; P -> ps(=ksl) [qtok][ktok] ----
  char* vs = qs;
  #pragma unroll
  for (int n = 0; n < 4; ++n) {
    int d = n * 16 + r16;
    float bvv = b2f(bqkvb[1024 + h * 64 + d]);
    #pragma unroll
    for (int mm = 0; mm < 2; ++mm) {
      int tok0 = half * 32 + mm * 16 + hi * 4;
      short4v pk;
      #pragma unroll
      for (int r = 0; r < 4; ++r) pk[r] = f2bs(acc[2][mm][n][r] + bvv);
      *(short4v*)(vs + d * 128 + (uint32_t)((2 * tok0) ^ ((d & 7) << 4))) = pk;
    }
  }
  char* ps = ksl;
  #pragma unroll
  for (int mm = 0; mm < 2; ++mm)
    #pragma unroll
    for (int n = 0; n < 4; ++n)
      #pragma unroll
      for (int rr = 0; rr < 4; ++rr) {
        int row = half * 32 + mm * 16 + hi * 4 + rr, col = n * 16 + r16;
        *(bf16*)(ps + row * 128 + (uint32_t)((2 * col) ^ ((row & 7) << 4))) =
            __float2bfloat16(s[mm][n][rr]);
      }
  __syncthreads();   // pair exchange: full v,P visible

  // ---- O = P @ V for this wave's 32 rows ----
  f32x4 o[2][4];
  #pragma unroll
  for (int mm = 0; mm < 2; ++mm)
    #pragma unroll
    for (int n = 0; n < 4; ++n) o[mm][n] = fz;
  #pragma unroll
  for (int ks = 0; ks < 2; ++ks) {
    const uint32_t cb = (uint32_t)((ks * 4 + hi) * 16);
    short8 pf[2], vf[4];
    #pragma unroll
    for (int mm = 0; mm < 2; ++mm)
      pf[mm] = *(const short8*)(ps + (half * 32 + mm * 16 + r16) * 128 + (cb ^ rx));
    #pragma unroll
    for (int n = 0; n < 4; ++n)
      vf[n] = *(const short8*)(vs + (n * 16 + r16) * 128 + (cb ^ rx));
    #pragma unroll
    for (int mm = 0; mm < 2; ++mm)
      #pragma unroll
      for (int n = 0; n < 4; ++n)
        o[mm][n] = MFMA16(pf[mm], vf[n], o[mm][n]);
  }

  // ---- O -> attnb (swizzled; pad rows finite garbage, discarded later) ----
  const size_t obase = (size_t)wi * 65536;
  #pragma unroll
  for (int mm = 0; mm < 2; ++mm)
    #pragma unroll
    for (int n = 0; n < 4; ++n) {
      int col = h * 64 + n * 16 + r16;
      #pragma unroll
      for (int r = 0; r < 4; ++r) {
        int row = half * 32 + mm * 16 + hi * 4 + r;
        *(bf16*)(attnb + obase + (size_t)row * 1024 +
                 (uint32_t)((2 * col) ^ ((row & 7) << 4))) =
            __float2bfloat16(o[mm][n][r]);
      }
    }
}

// ---------------------------------------------------------------------------
// k_out_gemm (round-5 proven: ~170 us, VGPR 80): out = attn @ wo^T + bo,
// f32 un-permute scatter. grid 1296x4; block 256 / 4 waves; LDS 32 KB.
// ---------------------------------------------------------------------------
__global__ __launch_bounds__(256) void k_out_gemm(
    const char* __restrict__ attnb,   // [165888][1024B] swizzled
    const char* __restrict__ wob,     // [512][1024B] swizzled
    const bf16* __restrict__ bob,     // [512]
    float* __restrict__ out)          // [8*15876][512] f32
{
  __shared__ __align__(16) char sA[16384];
  __shared__ __align__(16) char sB[16384];

  const int tid = threadIdx.x, lane = tid & 63, w = tid >> 6;
  const int r16 = lane & 15, hi = lane >> 4;
  const int mb = blockIdx.x % 1296, nb = blockIdx.x / 1296;

  const f32x4 fzero = {0.f, 0.f, 0.f, 0.f};
  f32x4 acc[4][4];
  #pragma unroll
  for (int m = 0; m < 4; ++m)
    #pragma unroll
    for (int n = 0; n < 4; ++n) acc[m][n] = fzero;

  const char* Abase = attnb + (size_t)mb * 131072;
  const char* Bbase = wob + (size_t)nb * 131072;

  for (int k0 = 0; k0 < 8; ++k0) {
    if (k0) __syncthreads();
    #pragma unroll
    for (int j = 0; j < 8; ++j) {
      int ch = w * 8 + j;
      if (ch < 16) {
        gl_lds16(Abase + (size_t)(ch * 8 + (lane >> 3)) * 1024 + k0 * 128 + (lane & 7) * 16,
                 sA + ch * 1024);
      } else {
        int c2 = ch - 16;
        gl_lds16(Bbase + (size_t)(c2 * 8 + (lane >> 3)) * 1024 + k0 * 128 + (lane & 7) * 16,
                 sB + c2 * 1024);
      }
    }
    __syncthreads();

    #pragma unroll
    for (int ks = 0; ks < 2; ++ks) {
      uint32_t cb = (uint32_t)((ks * 4 + hi) * 16) ^ ((r16 & 7u) << 4);
      short8 aF[4], bF[4];
      #pragma unroll
      for (int m = 0; m < 4; ++m)
        aF[m] = *reinterpret_cast<const short8*>(sA + ((w & 1) * 64 + m * 16 + r16) * 128 + cb);
      #pragma unroll
      for (int n = 0; n < 4; ++n)
        bF[n] = *reinterpret_cast<const short8*>(sB + ((w >> 1) * 64 + n * 16 + r16) * 128 + cb);
      #pragma unroll
      for (int m = 0; m < 4; ++m)
        #pragma unroll
        for (int n = 0; n < 4; ++n)
          acc[m][n] = MFMA16(aF[m], bF[n], acc[m][n]);
    }
  }

  const int wi = mb * 2 + (w & 1);
  const int bb = wi / 324, qr = wi - bb * 324, qi = qr / 18, qj = qr - qi * 18;
  const int rowBase = bb * 15876 + qi * 882 + qj * 7;
  const int colb = nb * 128 + (w >> 1) * 64;

  #pragma unroll
  for (int n = 0; n < 4; ++n) {
    int col = colb + n * 16 + r16;
    float bias = b2f(bob[col]);
    #pragma unroll
    for (int m = 0; m < 4; ++m)
      #pragma unroll
      for (int r = 0; r < 4; ++r) {
        int row = m * 16 + hi * 4 + r;
        if (row < 49)
          out[(size_t)(rowBase + (row / 7) * 126 + row % 7) * 512 + col] =
              acc[m][n][r] + bias;
      }
  }
}

extern "C" void kernel_launch(void* const* d_in, const int* in_sizes, int n_in,
                              void* d_out, int out_size, void* d_ws, size_t ws_size,
                              hipStream_t stream) {
  const float* x      = (const float*)d_in[0];
  const float* wqkv   = (const float*)d_in[1];
  const float* bqkv   = (const float*)d_in[2];
  const float* wo     = (const float*)d_in[3];
  const float* bo     = (const float*)d_in[4];
  const float* rpe    = (const float*)d_in[5];
  const int*   relidx = (const int*)d_in[6];

  char* ws = (char*)d_ws;
  const size_t OFF_ATTN = 256;
  const size_t SZ_ATTN  = 2592ull * 64 * 1024;        // 169,869,312
  const size_t OFF_WQKV = OFF_ATTN + SZ_ATTN;
  const size_t OFF_WO   = OFF_WQKV + 1536ull * 512 * 2;
  const size_t OFF_BQKV = OFF_WO + 512ull * 1024;
  const size_t OFF_BO   = OFF_BQKV + 3072;
  const size_t OFF_RPEW = OFF_BO + 1024;               // total ~172.4 MB

  char* attnb = ws + OFF_ATTN;
  bf16* wqkvb = (bf16*)(ws + OFF_WQKV);
  char* wob   = ws + OFF_WO;
  bf16* bqkvb = (bf16*)(ws + OFF_BQKV);
  bf16* bob   = (bf16*)(ws + OFF_BO);
  bf16* rpew  = (bf16*)(ws + OFF_RPEW);

  k_conv_w3<<<dim3(521), dim3(256), 0, stream>>>(wqkv, bqkv, wo, bo, rpe, relidx,
                                                 wqkvb, bqkvb, wob, bob, rpew);
  k_fused3<<<dim3(5184), dim3(512), 0, stream>>>(x, wqkvb, bqkvb, rpew, attnb);
  k_out_gemm<<<dim3(1296 * 4), dim3(256), 0, stream>>>(attnb, wob, bob, (float*)d_out);
}

// Round 10
// 747.947 us; speedup vs baseline: 2.6344x; 1.6979x over previous
//
#include <hip/hip_runtime.h>
#include <hip/hip_bf16.h>
#include <stdint.h>

typedef __attribute__((ext_vector_type(8))) short short8;
typedef __attribute__((ext_vector_type(4))) float f32x4;
typedef __hip_bfloat16 bf16;

#define MFMA16(a, b, c) __builtin_amdgcn_mfma_f32_16x16x32_bf16(a, b, c, 0, 0, 0)

__device__ __forceinline__ uint32_t swz(uint32_t row, uint32_t bir) {
  return bir ^ ((row & 7u) << 4);
}
__device__ __forceinline__ short f2bs(float v) {
  bf16 b = __float2bfloat16(v);
  return *reinterpret_cast<short*>(&b);
}
__device__ __forceinline__ float b2f(bf16 b) { return __bfloat162float(b); }

__device__ __forceinline__ short8 cvt8(f32x4 a, f32x4 b) {
  short8 v;
  v[0] = f2bs(a[0]); v[1] = f2bs(a[1]); v[2] = f2bs(a[2]); v[3] = f2bs(a[3]);
  v[4] = f2bs(b[0]); v[5] = f2bs(b[1]); v[6] = f2bs(b[2]); v[7] = f2bs(b[3]);
  return v;
}

// async global->LDS, 16B/lane; LDS dest = wave-uniform base + lane*16.
__device__ __forceinline__ void gl_lds16(const void* g, void* l) {
  __builtin_amdgcn_global_load_lds(
      (const __attribute__((address_space(1))) unsigned int*)g,
      (__attribute__((address_space(3))) unsigned int*)l, 16, 0, 0);
}

// ---------------------------------------------------------------------------
// conv_w: f32 weights -> SWIZZLED bf16 row-blobs (for gl_lds staging);
// biases -> linear bf16; rpe pre-gathered [8][49pad][64] (cols>=49 zero).
// ---------------------------------------------------------------------------
__global__ __launch_bounds__(256) void k_conv_w4(
    const float* __restrict__ wqkv, const float* __restrict__ bqkv,
    const float* __restrict__ wo,   const float* __restrict__ bo,
    const float* __restrict__ rpe,  const int* __restrict__ relidx,
    char* __restrict__ wqkvb, bf16* __restrict__ bqkvb,
    char* __restrict__ wob,   bf16* __restrict__ bob,
    bf16* __restrict__ rpew)
{
  int b = blockIdx.x, t = threadIdx.x;
  if (b < 384) {                       // wqkv: 1536x512 -> [1536][1024B] swz
    long i = (long)b * 2048 + t * 8;
    int row = (int)(i >> 9);
    uint32_t g = ((uint32_t)i & 511u) >> 3;
    f32x4 a = *(const f32x4*)(wqkv + i), c = *(const f32x4*)(wqkv + i + 4);
    *reinterpret_cast<short8*>(wqkvb + (size_t)row * 1024 + ((g * 16) ^ ((row & 7u) << 4))) = cvt8(a, c);
  } else if (b < 512) {                // wo: 512x512 -> [512][1024B] swz
    long i = (long)(b - 384) * 2048 + t * 8;
    int row = (int)(i >> 9);
    uint32_t g = ((uint32_t)i & 511u) >> 3;
    f32x4 a = *(const f32x4*)(wo + i), c = *(const f32x4*)(wo + i + 4);
    *reinterpret_cast<short8*>(wob + (size_t)row * 1024 + ((g * 16) ^ ((row & 7u) << 4))) = cvt8(a, c);
  } else if (b == 512) {
    for (int j = t; j < 1536; j += 256) bqkvb[j] = __float2bfloat16(bqkv[j]);
    for (int j = t; j < 512;  j += 256) bob[j]  = __float2bfloat16(bo[j]);
  } else {
    int h = b - 513;
    for (int e = t; e < 3136; e += 256) {
      int q = e >> 6, c = e & 63;
      float v = (c < 49) ? rpe[(long)relidx[q * 49 + c] * 8 + h] : 0.f;
      rpew[h * 3136 + e] = __float2bfloat16(v);
    }
  }
}

// ---------------------------------------------------------------------------
// conv_x: x f32 natural [127008][512] -> xb [127232 rows][1024B] pre-swizzled
// bf16, swizzle keyed by GLOBAL row (R&7). Rows >= 127008 zeroed.
// ---------------------------------------------------------------------------
__global__ __launch_bounds__(256) void k_conv_x3(
    const float* __restrict__ x, char* __restrict__ xb)
{
  int R  = blockIdx.x * 4 + (threadIdx.x >> 6);
  int c8 = threadIdx.x & 63;
  f32x4 a = {0.f, 0.f, 0.f, 0.f}, b = a;
  if (R < 127008) {
    a = *(const f32x4*)(x + (size_t)R * 512 + c8 * 8);
    b = *(const f32x4*)(x + (size_t)R * 512 + c8 * 8 + 4);
  }
  *reinterpret_cast<short8*>(xb + (size_t)R * 1024 + ((uint32_t)(c8 * 16) ^ ((R & 7u) << 4))) = cvt8(a, b);
}

// ---------------------------------------------------------------------------
// k_qkv_gemm3: per-batch chunk, natural-row M-tiles.
// grid 1536 = (125 mtiles x 12 nb, XCD-grouped). block 256 / 4 waves.
// ROUND-10 FIX: A-frag read XOR keyed by GLOBAL row ((r16+row0)&7), since
// row0 = cb*15876 + mtile*128 is only 4-aligned mod 8 for odd cb.
// ---------------------------------------------------------------------------
__global__ __launch_bounds__(256) void k_qkv_gemm3(
    const char* __restrict__ xb,      // [127232][1024B] swizzled (global-row key)
    const char* __restrict__ wqkvb,   // [1536][1024B] swizzled
    const bf16* __restrict__ bqkvb,   // [1536]
    char* __restrict__ blob,          // [3][324][8][8192B] chunk-local
    int cb_)                          // chunk batch 0..7
{
  __shared__ __align__(16) char sA[16384];
  __shared__ __align__(16) char sB[16384];

  const int tid = threadIdx.x, lane = tid & 63, w = tid >> 6;
  const int r16 = lane & 15, hi = lane >> 4;

  const int raw = blockIdx.x;
  const int xcd = raw & 7, grp = raw >> 3;
  const int nb = grp % 12, mg = grp / 12;
  const int mtile = mg * 8 + xcd;
  if (mtile >= 125) return;
  const int row0 = cb_ * 15876 + mtile * 128;

  const char* Abase = xb + (size_t)row0 * 1024;
  const char* Bbase = wqkvb + (size_t)nb * 131072;

  // A rows in sA local row l correspond to global row row0+l; the stored
  // swizzle key is ((row0+l)&7) = (r16&7)^(row0&7)  (row0&7 in {0,4}).
  const uint32_t rxA = ((uint32_t)((r16 + row0) & 7)) << 4;
  const uint32_t rxB = ((uint32_t)(r16 & 7)) << 4;

  const f32x4 fz = {0.f, 0.f, 0.f, 0.f};
  f32x4 acc[4][4];
  #pragma unroll
  for (int m = 0; m < 4; ++m)
    #pragma unroll
    for (int n = 0; n < 4; ++n) acc[m][n] = fz;

  for (int k0 = 0; k0 < 8; ++k0) {
    if (k0) __syncthreads();
    #pragma unroll
    for (int j = 0; j < 8; ++j) {
      int ch = w * 8 + j;
      if (ch < 16)
        gl_lds16(Abase + (size_t)(ch * 8 + (lane >> 3)) * 1024 + k0 * 128 + (lane & 7) * 16,
                 sA + ch * 1024);
      else {
        int c2 = ch - 16;
        gl_lds16(Bbase + (size_t)(c2 * 8 + (lane >> 3)) * 1024 + k0 * 128 + (lane & 7) * 16,
                 sB + c2 * 1024);
      }
    }
    __syncthreads();

    #pragma unroll
    for (int ks = 0; ks < 2; ++ks) {
      uint32_t cb = (uint32_t)((ks * 4 + hi) * 16);
      short8 aF[4], bF[4];
      #pragma unroll
      for (int m = 0; m < 4; ++m)
        aF[m] = *(const short8*)(sA + ((w & 1) * 64 + m * 16 + r16) * 128 + (cb ^ rxA));
      #pragma unroll
      for (int n = 0; n < 4; ++n)
        bF[n] = *(const short8*)(sB + ((w >> 1) * 64 + n * 16 + r16) * 128 + (cb ^ rxB));
      #pragma unroll
      for (int m = 0; m < 4; ++m)
        #pragma unroll
        for (int n = 0; n < 4; ++n)
          acc[m][n] = MFMA16(aF[m], bF[n], acc[m][n]);
    }
  }

  // epilogue: wave quadrant = rows (w&1)*64.., cols (w>>1)*64 of nb*128..
  const int gcol = nb * 128 + (w >> 1) * 64;   // 64-aligned
  const int t = gcol >> 9;                     // 0=q 1=k 2=v
  const int h = (gcol >> 6) & 7;
  const float scale = (t == 0) ? 0.125f : 1.0f;

  float bias4[4];
  #pragma unroll
  for (int n = 0; n < 4; ++n) bias4[n] = b2f(bqkvb[gcol + n * 16 + r16]);

  #pragma unroll
  for (int m = 0; m < 4; ++m)
    #pragma unroll
    for (int r = 0; r < 4; ++r) {
      int rnat = row0 + (w & 1) * 64 + m * 16 + hi * 4 + r;
      int rem = rnat - cb_ * 15876;
      if (rem >= 15876) continue;              // outside this chunk/batch
      int y = rem / 126, xc = rem - y * 126;
      int qi = y / 7, ph = y - qi * 7;
      int qj = xc / 7, pw = xc - qj * 7;
      int wiL = qi * 18 + qj, wrow = ph * 7 + pw;
      char* tile = blob + ((size_t)(t * 324 + wiL) * 8 + h) * 8192;
      #pragma unroll
      for (int n = 0; n < 4; ++n) {
        int d = n * 16 + r16;
        bf16 v = __float2bfloat16((acc[m][n][r] + bias4[n]) * scale);
        if (t < 2)
          *(bf16*)(tile + wrow * 128 + ((uint32_t)(2 * d) ^ ((wrow & 7u) << 4))) = v;
        else
          *(bf16*)(tile + wrow * 128 + 2 * d) = v;
      }
    }
}

// ---------------------------------------------------------------------------
// k_attn3: per (window, head) of chunk. Round-5 proven structure; output to
// natural-layout swizzled rows (wrow<49 only). block 256 / 4 waves.
// Blob rows 49..63 are stale/poison but benign: k-cols masked, P-cols zero.
// ---------------------------------------------------------------------------
__global__ __launch_bounds__(256) void k_attn3(
    const char* __restrict__ blob,    // [3][324][8][8192B]
    const bf16* __restrict__ rpew,    // [8][49pad][64]
    char* __restrict__ attnb,         // [127104][1024B] swizzled natural rows
    int cb_)
{
  __shared__ __align__(16) char sQ[8192];
  __shared__ __align__(16) char sK[8192];
  __shared__ __align__(16) char sV[8192];
  __shared__ __align__(16) char sP[8192];

  const int tid = threadIdx.x, lane = tid & 63, w = tid >> 6;
  const int r16 = lane & 15, hi = lane >> 4;
  const int wiL = blockIdx.x >> 3, h = blockIdx.x & 7;

  const char* qb = blob + ((size_t)(0 * 324 + wiL) * 8 + h) * 8192;
  const char* kb = blob + ((size_t)(1 * 324 + wiL) * 8 + h) * 8192;
  const char* vb = blob + ((size_t)(2 * 324 + wiL) * 8 + h) * 8192;

  #pragma unroll
  for (int j = 0; j < 6; ++j) {
    int ch = w * 6 + j;
    int rg = ch >> 3, sub = ch & 7;
    const char* src = (rg == 0 ? qb : rg == 1 ? kb : vb) + sub * 1024 + lane * 16;
    char* dst = (rg == 0 ? sQ : rg == 1 ? sK : sV) + sub * 1024;
    gl_lds16(src, dst);
  }
  __syncthreads();

  const f32x4 fz = {0.f, 0.f, 0.f, 0.f};

  // S = q k^T (wave w owns q-rows w*16..)
  f32x4 s[4];
  #pragma unroll
  for (int n = 0; n < 4; ++n) s[n] = fz;
  #pragma unroll
  for (int k0 = 0; k0 < 2; ++k0) {
    int qrow = w * 16 + r16;
    short8 a = *(const short8*)(sQ + qrow * 128 + swz(qrow, k0 * 64 + hi * 16));
    #pragma unroll
    for (int n = 0; n < 4; ++n) {
      int krow = n * 16 + r16;
      short8 kf = *(const short8*)(sK + krow * 128 + swz(krow, k0 * 64 + hi * 16));
      s[n] = MFMA16(a, kf, s[n]);
    }
  }

  // +RPE, mask, in-register softmax
  #pragma unroll
  for (int n = 0; n < 4; ++n) {
    int col = n * 16 + r16;
    #pragma unroll
    for (int rr = 0; rr < 4; ++rr) {
      int qrow = w * 16 + hi * 4 + rr;
      int qc = qrow < 49 ? qrow : 48;
      float sv = s[n][rr] + b2f(rpew[h * 3136 + qc * 64 + col]);
      if (col >= 49) sv = -1e30f;
      s[n][rr] = sv;
    }
  }
  #pragma unroll
  for (int rr = 0; rr < 4; ++rr) {
    float mx = fmaxf(fmaxf(s[0][rr], s[1][rr]), fmaxf(s[2][rr], s[3][rr]));
    mx = fmaxf(mx, __shfl_xor(mx, 1));
    mx = fmaxf(mx, __shfl_xor(mx, 2));
    mx = fmaxf(mx, __shfl_xor(mx, 4));
    mx = fmaxf(mx, __shfl_xor(mx, 8));
    float su = 0.f;
    #pragma unroll
    for (int n = 0; n < 4; ++n) {
      float e = __expf(s[n][rr] - mx);
      s[n][rr] = e;
      su += e;
    }
    su += __shfl_xor(su, 1);
    su += __shfl_xor(su, 2);
    su += __shfl_xor(su, 4);
    su += __shfl_xor(su, 8);
    float inv = 1.f / su;
    #pragma unroll
    for (int n = 0; n < 4; ++n) s[n][rr] *= inv;
  }

  // P -> wave-private slab (A-frag layout)
  char* pw = sP + w * 2048;
  #pragma unroll
  for (int n = 0; n < 4; ++n)
    #pragma unroll
    for (int rr = 0; rr < 4; ++rr) {
      int rl = hi * 4 + rr, col = n * 16 + r16;
      *(bf16*)(pw + rl * 128 + swz(rl, 2 * col)) = __float2bfloat16(s[n][rr]);
    }
  __syncthreads();  // everyone done reading sQ/sK

  // cooperative transpose: sV (linear [tok][d]) -> sVt(=sQ) [d][tok] swizzled
  char* sVt = sQ;
  {
    int k = tid >> 2, c0 = (tid & 3) * 16;
    short8 v0 = *(const short8*)(sV + k * 128 + 2 * c0);
    short8 v1 = *(const short8*)(sV + k * 128 + 2 * c0 + 16);
    #pragma unroll
    for (int e = 0; e < 8; ++e) {
      int c = c0 + e;
      *(short*)(sVt + c * 128 + ((uint32_t)(2 * k) ^ ((c & 7u) << 4))) = v0[e];
      int c2 = c0 + 8 + e;
      *(short*)(sVt + c2 * 128 + ((uint32_t)(2 * k) ^ ((c2 & 7u) << 4))) = v1[e];
    }
  }
  __syncthreads();

  // O = P @ V
  f32x4 o[4];
  #pragma unroll
  for (int n = 0; n < 4; ++n) o[n] = fz;
  #pragma unroll
  for (int k0 = 0; k0 < 2; ++k0) {
    short8 a = *(const short8*)(pw + r16 * 128 + swz(r16, k0 * 64 + hi * 16));
    #pragma unroll
    for (int n = 0; n < 4; ++n) {
      int d = n * 16 + r16;
      short8 vf = *(const short8*)(sVt + d * 128 + swz(d, k0 * 64 + hi * 16));
      o[n] = MFMA16(a, vf, o[n]);
    }
  }

  // write O -> natural swizzled rows (only wrow < 49); key = global row &7
  const int qi = wiL / 18, qj = wiL - qi * 18;
  const int rowBase = cb_ * 15876 + qi * 882 + qj * 7;
  #pragma unroll
  for (int n = 0; n < 4; ++n) {
    int d = n * 16 + r16;
    #pragma unroll
    for (int r = 0; r < 4; ++r) {
      int wrow = w * 16 + hi * 4 + r;
      if (wrow < 49) {
        int rnat = rowBase + (wrow / 7) * 126 + wrow % 7;
        *(bf16*)(attnb + (size_t)rnat * 1024 +
                 ((uint32_t)(h * 128 + 2 * d) ^ ((rnat & 7u) << 4))) =
            __float2bfloat16(o[n][r]);
      }
    }
  }
}

// ---------------------------------------------------------------------------
// k_out_gemm3: out = attn @ wo^T + bo, natural coalesced f32 epilogue.
// grid 4000 = 993 mtiles x 4 nb XCD-grouped (A L2-reuse); block 256 / 4 waves.
// row0 = mtile*128 is 8-aligned -> local swizzle key valid for A and B.
// ---------------------------------------------------------------------------
__global__ __launch_bounds__(256) void k_out_gemm3(
    const char* __restrict__ attnb,   // [127104][1024B] swizzled
    const char* __restrict__ wob,     // [512][1024B] swizzled
    const bf16* __restrict__ bob,     // [512]
    float* __restrict__ out)          // [127008][512] f32
{
  __shared__ __align__(16) char sA[16384];
  __shared__ __align__(16) char sB[16384];

  const int tid = threadIdx.x, lane = tid & 63, w = tid >> 6;
  const int r16 = lane & 15, hi = lane >> 4;

  const int raw = blockIdx.x;
  const int xcd = raw & 7, grp = raw >> 3;
  const int nb = grp & 3, mg = grp >> 2;
  const int mtile = mg * 8 + xcd;
  if (mtile >= 993) return;
  const int row0 = mtile * 128;

  const char* Abase = attnb + (size_t)row0 * 1024;
  const char* Bbase = wob + (size_t)nb * 131072;

  const f32x4 fz = {0.f, 0.f, 0.f, 0.f};
  f32x4 acc[4][4];
  #pragma unroll
  for (int m = 0; m < 4; ++m)
    #pragma unroll
    for (int n = 0; n < 4; ++n) acc[m][n] = fz;

  for (int k0 = 0; k0 < 8; ++k0) {
    if (k0) __syncthreads();
    #pragma unroll
    for (int j = 0; j < 8; ++j) {
      int ch = w * 8 + j;
      if (ch < 16)
        gl_lds16(Abase + (size_t)(ch * 8 + (lane >> 3)) * 1024 + k0 * 128 + (lane & 7) * 16,
                 sA + ch * 1024);
      else {
        int c2 = ch - 16;
        gl_lds16(Bbase + (size_t)(c2 * 8 + (lane >> 3)) * 1024 + k0 * 128 + (lane & 7) * 16,
                 sB + c2 * 1024);
      }
    }
    __syncthreads();

    #pragma unroll
    for (int ks = 0; ks < 2; ++ks) {
      uint32_t cb = (uint32_t)((ks * 4 + hi) * 16) ^ ((r16 & 7u) << 4);
      short8 aF[4], bF[4];
      #pragma unroll
      for (int m = 0; m < 4; ++m)
        aF[m] = *(const short8*)(sA + ((w & 1) * 64 + m * 16 + r16) * 128 + cb);
      #pragma unroll
      for (int n = 0; n < 4; ++n)
        bF[n] = *(const short8*)(sB + ((w >> 1) * 64 + n * 16 + r16) * 128 + cb);
      #pragma unroll
      for (int m = 0; m < 4; ++m)
        #pragma unroll
        for (int n = 0; n < 4; ++n)
          acc[m][n] = MFMA16(aF[m], bF[n], acc[m][n]);
    }
  }

  // epilogue: natural coalesced f32 stores
  #pragma unroll
  for (int n = 0; n < 4; ++n) {
    int col = nb * 128 + (w >> 1) * 64 + n * 16 + r16;
    float bias = b2f(bob[col]);
    #pragma unroll
    for (int m = 0; m < 4; ++m)
      #pragma unroll
      for (int r = 0; r < 4; ++r) {
        int row = row0 + (w & 1) * 64 + m * 16 + hi * 4 + r;
        if (row < 127008)
          out[(size_t)row * 512 + col] = acc[m][n][r] + bias;
      }
  }
}

extern "C" void kernel_launch(void* const* d_in, const int* in_sizes, int n_in,
                              void* d_out, int out_size, void* d_ws, size_t ws_size,
                              hipStream_t stream) {
  const float* x      = (const float*)d_in[0];
  const float* wqkv   = (const float*)d_in[1];
  const float* bqkv   = (const float*)d_in[2];
  const float* wo     = (const float*)d_in[3];
  const float* bo     = (const float*)d_in[4];
  const float* rpe    = (const float*)d_in[5];
  const int*   relidx = (const int*)d_in[6];

  char* ws = (char*)d_ws;
  const size_t OFF_XB    = 256;
  const size_t SZ_XB     = 127232ull * 1024;            // 130,285,568
  const size_t OFF_ATTNB = OFF_XB + SZ_XB;
  const size_t SZ_ATTNB  = 127104ull * 1024;            // 130,154,496
  const size_t OFF_BLOB  = OFF_ATTNB + SZ_ATTNB;
  const size_t SZ_BLOB   = 3ull * 324 * 8 * 8192;       // 63,700,992
  const size_t OFF_WQKV  = OFF_BLOB + SZ_BLOB;
  const size_t OFF_WO    = OFF_WQKV + 1536ull * 1024;
  const size_t OFF_BQKV  = OFF_WO + 512ull * 1024;
  const size_t OFF_BO    = OFF_BQKV + 3072;
  const size_t OFF_RPEW  = OFF_BO + 1024;               // total ~326.3 MB

  char* xb    = ws + OFF_XB;
  char* attnb = ws + OFF_ATTNB;
  char* blob  = ws + OFF_BLOB;
  char* wqkvb = ws + OFF_WQKV;
  char* wob   = ws + OFF_WO;
  bf16* bqkvb = (bf16*)(ws + OFF_BQKV);
  bf16* bob   = (bf16*)(ws + OFF_BO);
  bf16* rpew  = (bf16*)(ws + OFF_RPEW);

  k_conv_w4<<<dim3(521), dim3(256), 0, stream>>>(wqkv, bqkv, wo, bo, rpe, relidx,
                                                 wqkvb, bqkvb, wob, bob, rpew);
  k_conv_x3<<<dim3(31808), dim3(256), 0, stream>>>(x, xb);
  for (int b = 0; b < 8; ++b) {
    k_qkv_gemm3<<<dim3(1536), dim3(256), 0, stream>>>(xb, wqkvb, bqkvb, blob, b);
    k_attn3<<<dim3(2592), dim3(256), 0, stream>>>(blob, rpew, attnb, b);
  }
  k_out_gemm3<<<dim3(4000), dim3(256), 0, stream>>>(attnb, wob, bob, (float*)d_out);
}